// Round 2
// baseline (707.030 us; speedup 1.0000x reference)
//
#include <hip/hip_runtime.h>

typedef unsigned short u16;
typedef __attribute__((ext_vector_type(4)))  unsigned int u32x4;
typedef __attribute__((ext_vector_type(4)))  float        f32x4;
typedef __attribute__((ext_vector_type(4)))  u16          u16x4;
typedef __attribute__((ext_vector_type(8)))  u16          u16x8;
typedef __attribute__((ext_vector_type(8)))  __bf16       bf16x8;
typedef __attribute__((ext_vector_type(16))) float        f32x16;

#define NB 2
#define NH 8
#define NS 2048
#define ND 128

static __device__ __forceinline__ u16 f2b(float x) {
  return __builtin_bit_cast(u16, (__bf16)x);
}

// ---------------- merged pre-pass: k f32->bf16 ; v f32 -> vt bf16 transposed ----------------
__global__ __launch_bounds__(256) void prepass(const float* __restrict__ k,
                                               const float* __restrict__ v,
                                               u16* __restrict__ kb, u16* __restrict__ vt) {
  const int bid = blockIdx.x;
  const int t = threadIdx.x;
  if (bid < 4096) {                                  // k: 4M elems as f32x4
    int i = bid * 256 + t;
    f32x4 x = ((const f32x4*)k)[i];
    u16x4 o;
    o[0] = f2b(x[0]); o[1] = f2b(x[1]); o[2] = f2b(x[2]); o[3] = f2b(x[3]);
    ((u16x4*)kb)[i] = o;
    return;
  }
  // v transpose: [bh][s][d] -> [bh][d][s]
  __shared__ u16 Lt[128][40];
  const int vb = bid - 4096;                         // 1024 blocks
  const int bh = vb >> 6;
  const int s0 = (vb & 63) * 32;
  const float* src = v + (size_t)(bh * NS + s0) * ND;
  const int srow = t >> 3;
#pragma unroll
  for (int it = 0; it < 4; ++it) {
    int c4 = (t & 7) + 8 * it;
    f32x4 x = *(const f32x4*)(src + srow * ND + c4 * 4);
#pragma unroll
    for (int jj = 0; jj < 4; ++jj) Lt[c4 * 4 + jj][srow] = f2b(x[jj]);
  }
  __syncthreads();
  const int d = t >> 1, sh = t & 1;
  u32x4 a  = *(const u32x4*)&Lt[d][sh * 16];
  u32x4 bq = *(const u32x4*)&Lt[d][sh * 16 + 8];
  u16* dst = vt + (size_t)(bh * ND + d) * NS + s0 + sh * 16;
  *(u32x4*)dst       = a;
  *(u32x4*)(dst + 8) = bq;
}

// ---------------- async global->LDS 16B ----------------
static __device__ __forceinline__ void gll16(u16* l, const u16* g) {
  __builtin_amdgcn_global_load_lds((const __attribute__((address_space(1))) void*)g,
                                   (__attribute__((address_space(3))) void*)l, 16, 0, 0);
}

// ---------------- main fused kernel ----------------
// grid 256: h = bid&7 (XCD), b = (bid>>3)&1, qt = bid>>4 -> 128 q-rows
// 4 waves, wave w owns q-rows [q0+32w, +32), full 2048-kv sweep, KVBLK=32
__global__ __launch_bounds__(256, 4) void retention_main(
    const float* __restrict__ qf32, const u16* __restrict__ kb, const u16* __restrict__ vt,
    const float* __restrict__ omask, float* __restrict__ out) {
  __shared__ u16 Kls[2][32][128];   // 16 KB, chunk-XOR swizzled (source side)
  __shared__ u16 Vls[2][128][32];   // 16 KB, chunk-XOR swizzled (source side)
  __shared__ u16 Pls[4][32][32];    //  8 KB, XOR-swizzled
                                    // total 40 KB -> 4 blocks/CU

  const int tid  = threadIdx.x;
  const int w    = tid >> 6;
  const int lane = tid & 63;
  const int l31  = lane & 31;
  const int hh   = lane >> 5;

  const int h  = blockIdx.x & 7;
  const int b  = (blockIdx.x >> 3) & 1;
  const int qt = blockIdx.x >> 4;
  const int q0 = qt * 128;
  const int qw = q0 + w * 32;

  // ---- Q fragments from f32 global (one-time): row = qw + l31, k = 16ka+8hh+j
  bf16x8 qf[8];
  {
    const float* qrow = qf32 + ((size_t)((b * NH + h) * NS) + qw + l31) * ND + hh * 8;
#pragma unroll
    for (int ka = 0; ka < 8; ++ka) {
      f32x4 x0 = *(const f32x4*)(qrow + ka * 16);
      f32x4 x1 = *(const f32x4*)(qrow + ka * 16 + 4);
      u16x8 o;
      o[0] = f2b(x0[0]); o[1] = f2b(x0[1]); o[2] = f2b(x0[2]); o[3] = f2b(x0[3]);
      o[4] = f2b(x1[0]); o[5] = f2b(x1[1]); o[6] = f2b(x1[2]); o[7] = f2b(x1[3]);
      qf[ka] = __builtin_bit_cast(bf16x8, o);
    }
  }

  f32x16 acc[4];
#pragma unroll
  for (int n = 0; n < 4; ++n)
#pragma unroll
    for (int i = 0; i < 16; ++i) acc[n][i] = 0.0f;

  const u16* kg0 = kb + (size_t)((b * NH + h) * NS) * ND;
  const u16* vg0 = vt + (size_t)((b * NH + h) * ND) * NS;
  const float* mrow0 = omask + (size_t)h * NS * NS + (size_t)qw * NS;

  auto STAGE = [&](int T, int db) {
    // K tile: 32 rows x 256B; LDS(j,c) <- global chunk c^(j&15)
    const u16* kg = kg0 + (size_t)T * 32 * ND;
    u16* kl = &Kls[db][0][0];
#pragma unroll
    for (int i = 0; i < 2; ++i) {
      int r0 = w * 8 + i * 4;
      int jr = r0 + (lane >> 4);
      int cc = (lane & 15) ^ (jr & 15);
      gll16(kl + r0 * 128, kg + jr * 128 + cc * 8);
    }
    // Vt tile: 128 rows x 64B; LDS(d,c) <- global chunk c^(d&3)
    const u16* vg = vg0 + T * 32;
    u16* vl = &Vls[db][0][0];
#pragma unroll
    for (int i = 0; i < 2; ++i) {
      int r0 = w * 32 + i * 16;
      int rr = r0 + (lane >> 2);
      int cc = (lane & 3) ^ (rr & 3);
      gll16(vl + r0 * 32, vg + (size_t)rr * NS + cc * 8);
    }
  };

  float m[16];
  auto LOADM = [&](int T) {
    const float* mrow = mrow0 + T * 32 + l31;
#pragma unroll
    for (int r16 = 0; r16 < 16; ++r16) {
      int qrow = (r16 & 3) + 8 * (r16 >> 2) + 4 * hh;   // D-frag row
      m[r16] = mrow[(size_t)qrow * NS];
    }
  };

  auto COMPUTE = [&](int db) {
    const u16* Kt = &Kls[db][0][0];
    const u16* Vw = &Vls[db][0][0];
    f32x16 s;
#pragma unroll
    for (int i = 0; i < 16; ++i) s[i] = 0.0f;
    // QK^T: B-frag col j=l31, chunk (2ka+hh)^(j&15)
#pragma unroll
    for (int ka = 0; ka < 8; ++ka) {
      int cc = (2 * ka + hh) ^ (l31 & 15);
      bf16x8 kf = __builtin_bit_cast(bf16x8, *(const u32x4*)(Kt + l31 * 128 + cc * 8));
      s = __builtin_amdgcn_mfma_f32_32x32x16_bf16(qf[ka], kf, s, 0, 0, 0);
    }
    // P = S * mask -> bf16 -> swizzled LDS
    u16* Pw = &Pls[w][0][0];
#pragma unroll
    for (int r16 = 0; r16 < 16; ++r16) {
      int qrow = (r16 & 3) + 8 * (r16 >> 2) + 4 * hh;
      int idx  = qrow * 32 + (l31 ^ (((qrow >> 1) & 3) << 3));
      Pw[idx] = f2b(s[r16] * m[r16]);
    }
    asm volatile("" ::: "memory");
    bf16x8 pa[2];
#pragma unroll
    for (int kk = 0; kk < 2; ++kk) {
      int idx = l31 * 32 + ((8 * hh + 16 * kk) ^ (((l31 >> 1) & 3) << 3));
      pa[kk] = __builtin_bit_cast(bf16x8, *(const u32x4*)(Pw + idx));
    }
    // PV: B-frag col d2=32n+l31, chunk (2kk+hh)^(d2&3)
#pragma unroll
    for (int n = 0; n < 4; ++n) {
#pragma unroll
      for (int kk = 0; kk < 2; ++kk) {
        int cc = (2 * kk + hh) ^ (l31 & 3);
        bf16x8 vf = __builtin_bit_cast(bf16x8, *(const u32x4*)(Vw + (n * 32 + l31) * 32 + cc * 8));
        acc[n] = __builtin_amdgcn_mfma_f32_32x32x16_bf16(pa[kk], vf, acc[n], 0, 0, 0);
      }
    }
  };

  // ---- pipeline: 64 tiles, 1 barrier/tile ----
  STAGE(0, 0);
  __syncthreads();
#pragma unroll 1
  for (int t = 0; t < 64; ++t) {
    int cur = t & 1;
    LOADM(t);                          // mask for current tile (issue first)
    if (t < 63) STAGE(t + 1, cur ^ 1); // prefetch next tile
    COMPUTE(cur);
    __syncthreads();
  }

  // ---- epilogue: per-wave RMSNorm + store (no cross-wave combine) ----
  float ss[16];
#pragma unroll
  for (int r16 = 0; r16 < 16; ++r16) {
    float tt = 0.0f;
#pragma unroll
    for (int n = 0; n < 4; ++n) tt += acc[n][r16] * acc[n][r16];
    ss[r16] = tt;
  }
#pragma unroll
  for (int msk = 1; msk <= 16; msk <<= 1)
#pragma unroll
    for (int r16 = 0; r16 < 16; ++r16) ss[r16] += __shfl_xor(ss[r16], msk);
#pragma unroll
  for (int r16 = 0; r16 < 16; ++r16)
    ss[r16] = rsqrtf(ss[r16] * (1.0f / 128.0f) + 1e-6f);
  float* orow = out + ((size_t)((b * NH + h) * NS) + qw) * ND;
#pragma unroll
  for (int n = 0; n < 4; ++n)
#pragma unroll
    for (int r16 = 0; r16 < 16; ++r16) {
      int qrow = (r16 & 3) + 8 * (r16 >> 2) + 4 * hh;
      orow[(size_t)qrow * ND + n * 32 + l31] = acc[n][r16] * ss[r16];
    }
}

extern "C" void kernel_launch(void* const* d_in, const int* in_sizes, int n_in,
                              void* d_out, int out_size, void* d_ws, size_t ws_size,
                              hipStream_t stream) {
  const float* q  = (const float*)d_in[0];
  const float* k  = (const float*)d_in[1];
  const float* v  = (const float*)d_in[2];
  const float* om = (const float*)d_in[3];
  float* out = (float*)d_out;

  const int NELT = NB * NH * NS * ND;       // 4,194,304
  u16* kbuf = (u16*)d_ws;
  u16* vtb  = kbuf + NELT;

  prepass<<<4096 + 1024, 256, 0, stream>>>(k, v, kbuf, vtb);
  retention_main<<<256, 256, 0, stream>>>(q, kbuf, vtb, om, out);
}

// Round 3
// 392.401 us; speedup vs baseline: 1.8018x; 1.8018x over previous
//
#include <hip/hip_runtime.h>

typedef unsigned short u16;
typedef __attribute__((ext_vector_type(4)))  unsigned int u32x4;
typedef __attribute__((ext_vector_type(4)))  float        f32x4;
typedef __attribute__((ext_vector_type(4)))  u16          u16x4;
typedef __attribute__((ext_vector_type(8)))  u16          u16x8;
typedef __attribute__((ext_vector_type(8)))  __bf16       bf16x8;
typedef __attribute__((ext_vector_type(16))) float        f32x16;

#define NB 2
#define NH 8
#define NS 2048
#define ND 128

static __device__ __forceinline__ u16 f2b(float x) {
  return __builtin_bit_cast(u16, (__bf16)x);
}

// ---------------- merged pre-pass: k f32->bf16 ; v f32 -> vt bf16 transposed ----------------
__global__ __launch_bounds__(256) void prepass(const float* __restrict__ k,
                                               const float* __restrict__ v,
                                               u16* __restrict__ kb, u16* __restrict__ vt) {
  const int bid = blockIdx.x;
  const int t = threadIdx.x;
  if (bid < 4096) {                                  // k: 4M elems as f32x4
    int i = bid * 256 + t;
    f32x4 x = ((const f32x4*)k)[i];
    u16x4 o;
    o[0] = f2b(x[0]); o[1] = f2b(x[1]); o[2] = f2b(x[2]); o[3] = f2b(x[3]);
    ((u16x4*)kb)[i] = o;
    return;
  }
  // v transpose: [bh][s][d] -> [bh][d][s]
  __shared__ u16 Lt[128][40];
  const int vb = bid - 4096;                         // 1024 blocks
  const int bh = vb >> 6;
  const int s0 = (vb & 63) * 32;
  const float* src = v + (size_t)(bh * NS + s0) * ND;
  const int srow = t >> 3;
#pragma unroll
  for (int it = 0; it < 4; ++it) {
    int c4 = (t & 7) + 8 * it;
    f32x4 x = *(const f32x4*)(src + srow * ND + c4 * 4);
#pragma unroll
    for (int jj = 0; jj < 4; ++jj) Lt[c4 * 4 + jj][srow] = f2b(x[jj]);
  }
  __syncthreads();
  const int d = t >> 1, sh = t & 1;
  u32x4 a  = *(const u32x4*)&Lt[d][sh * 16];
  u32x4 bq = *(const u32x4*)&Lt[d][sh * 16 + 8];
  u16* dst = vt + (size_t)(bh * ND + d) * NS + s0 + sh * 16;
  *(u32x4*)dst       = a;
  *(u32x4*)(dst + 8) = bq;
}

// ---------------- async global->LDS 16B ----------------
static __device__ __forceinline__ void gll16(u16* l, const u16* g) {
  __builtin_amdgcn_global_load_lds((const __attribute__((address_space(1))) void*)g,
                                   (__attribute__((address_space(3))) void*)l, 16, 0, 0);
}

// ---------------- main fused kernel ----------------
// grid 256: h = bid&7 (XCD), b = (bid>>3)&1, qt = bid>>4 -> 128 q-rows
// 16 waves: qw = w&3 (32 q-rows), jp = w>>2 (kv parity of 4). 16 steps x 4 tiles.
__global__ __launch_bounds__(1024, 2) void retention_main(
    const float* __restrict__ qf32, const u16* __restrict__ kb, const u16* __restrict__ vt,
    const float* __restrict__ omask, float* __restrict__ out) {
  __shared__ u16 Kls[2][4][32][128];   // 64 KB (chunk-XOR swizzled via source)
  __shared__ u16 Vls[2][4][128][32];   // 64 KB (chunk-XOR swizzled via source)
  __shared__ u16 Pls[16][32][32];      // 32 KB (XOR-swizzled)  -> 160 KB total

  const int tid  = threadIdx.x;
  const int w    = tid >> 6;
  const int lane = tid & 63;
  const int l31  = lane & 31;
  const int hh   = lane >> 5;

  const int h  = blockIdx.x & 7;
  const int b  = (blockIdx.x >> 3) & 1;
  const int qt = blockIdx.x >> 4;
  const int q0 = qt * 128;

  const int qw = w & 3;
  const int jp = w >> 2;

  // ---- Q fragments from f32 global (one-time): row = q0+qw*32+l31, k = 16ka+8hh+j
  bf16x8 qf[8];
  {
    const float* qrow = qf32 + ((size_t)((b * NH + h) * NS) + q0 + qw * 32 + l31) * ND + hh * 8;
#pragma unroll
    for (int ka = 0; ka < 8; ++ka) {
      f32x4 x0 = *(const f32x4*)(qrow + ka * 16);
      f32x4 x1 = *(const f32x4*)(qrow + ka * 16 + 4);
      u16x8 o;
      o[0] = f2b(x0[0]); o[1] = f2b(x0[1]); o[2] = f2b(x0[2]); o[3] = f2b(x0[3]);
      o[4] = f2b(x1[0]); o[5] = f2b(x1[1]); o[6] = f2b(x1[2]); o[7] = f2b(x1[3]);
      qf[ka] = __builtin_bit_cast(bf16x8, o);
    }
  }

  f32x16 acc[4];
#pragma unroll
  for (int n = 0; n < 4; ++n)
#pragma unroll
    for (int i = 0; i < 16; ++i) acc[n][i] = 0.0f;

  const u16* kg0 = kb + (size_t)((b * NH + h) * NS) * ND;
  const u16* vg0 = vt + (size_t)((b * NH + h) * ND) * NS;
  const float* mrow0 = omask + (size_t)h * NS * NS + (size_t)(q0 + qw * 32) * NS;

  // staging roles: wave w stages tile sj = w>>2 (== jp), row-group sr = w&3 (== qw)
  auto STAGE = [&](int step, int db) {
    const int T = 4 * step + jp;
    const u16* kg = kg0 + (size_t)T * 32 * ND;
    u16* kl = &Kls[db][jp][0][0];
#pragma unroll
    for (int i = 0; i < 2; ++i) {
      int r0 = qw * 8 + i * 4;
      int jr = r0 + (lane >> 4);
      int cc = (lane & 15) ^ (jr & 15);
      gll16(kl + r0 * 128, kg + jr * 128 + cc * 8);
    }
    const u16* vg = vg0 + T * 32;
    u16* vl = &Vls[db][jp][0][0];
#pragma unroll
    for (int i = 0; i < 2; ++i) {
      int r0 = qw * 32 + i * 16;
      int rr = r0 + (lane >> 2);
      int cc = (lane & 3) ^ (rr & 3);
      gll16(vl + r0 * 32, vg + (size_t)rr * NS + cc * 8);
    }
  };

  float m[16];
  auto LOADM = [&](int step) {
    const int T = 4 * step + jp;
    const float* mrow = mrow0 + T * 32 + l31;
#pragma unroll
    for (int r16 = 0; r16 < 16; ++r16) {
      int qrow = (r16 & 3) + 8 * (r16 >> 2) + 4 * hh;   // D-frag row
      m[r16] = mrow[(size_t)qrow * NS];
    }
  };

  // ---- pipeline: 16 steps, 4 tiles/step, 1 barrier/step ----
  LOADM(0);
  STAGE(0, 0);
  __syncthreads();
#pragma unroll 1
  for (int t = 0; t < 16; ++t) {
    const int db = t & 1;
    if (t < 15) STAGE(t + 1, db ^ 1);
    const u16* Kt = &Kls[db][jp][0][0];
    const u16* Vw = &Vls[db][jp][0][0];
    f32x16 s;
#pragma unroll
    for (int i = 0; i < 16; ++i) s[i] = 0.0f;
    // QK^T: B-frag col j=l31, chunk (2ka+hh)^(j&15)
    __builtin_amdgcn_s_setprio(1);
#pragma unroll
    for (int ka = 0; ka < 8; ++ka) {
      int cc = (2 * ka + hh) ^ (l31 & 15);
      bf16x8 kf = __builtin_bit_cast(bf16x8, *(const u32x4*)(Kt + l31 * 128 + cc * 8));
      s = __builtin_amdgcn_mfma_f32_32x32x16_bf16(qf[ka], kf, s, 0, 0, 0);
    }
    __builtin_amdgcn_s_setprio(0);
    // P = S * mask -> bf16 -> swizzled LDS
    u16* Pw = &Pls[w][0][0];
#pragma unroll
    for (int r16 = 0; r16 < 16; ++r16) {
      int qrow = (r16 & 3) + 8 * (r16 >> 2) + 4 * hh;
      int idx  = qrow * 32 + (l31 ^ (((qrow >> 1) & 3) << 3));
      Pw[idx] = f2b(s[r16] * m[r16]);
    }
    if (t < 15) LOADM(t + 1);          // mask prefetch: lands during PV + next QK
    asm volatile("" ::: "memory");
    bf16x8 pa[2];
#pragma unroll
    for (int kk = 0; kk < 2; ++kk) {
      int idx = l31 * 32 + ((8 * hh + 16 * kk) ^ (((l31 >> 1) & 3) << 3));
      pa[kk] = __builtin_bit_cast(bf16x8, *(const u32x4*)(Pw + idx));
    }
    // PV: B-frag col d2=32n+l31, chunk (2kk+hh)^(d2&3)
    __builtin_amdgcn_s_setprio(1);
#pragma unroll
    for (int n = 0; n < 4; ++n) {
#pragma unroll
      for (int kk = 0; kk < 2; ++kk) {
        int cc = (2 * kk + hh) ^ (l31 & 3);
        bf16x8 vf = __builtin_bit_cast(bf16x8, *(const u32x4*)(Vw + (n * 32 + l31) * 32 + cc * 8));
        acc[n] = __builtin_amdgcn_mfma_f32_32x32x16_bf16(pa[kk], vf, acc[n], 0, 0, 0);
      }
    }
    __builtin_amdgcn_s_setprio(0);
    __syncthreads();
  }

  // ---- epilogue: combine jp partials in LDS, RMSNorm, store (jp==0 waves) ----
  float* redK = (float*)&Kls[0][0][0][0];   // 64 KB = 4 qw x (32x128) f32
  float* redV = (float*)&Vls[0][0][0][0];
  auto DUMP = [&](float* red) {
#pragma unroll
    for (int n = 0; n < 4; ++n)
#pragma unroll
      for (int r16 = 0; r16 < 16; ++r16) {
        int qrow = (r16 & 3) + 8 * (r16 >> 2) + 4 * hh;
        red[(size_t)(qw * 32 + qrow) * 128 + n * 32 + l31] = acc[n][r16];
      }
  };
  auto ADD = [&](const float* red) {
#pragma unroll
    for (int n = 0; n < 4; ++n)
#pragma unroll
      for (int r16 = 0; r16 < 16; ++r16) {
        int qrow = (r16 & 3) + 8 * (r16 >> 2) + 4 * hh;
        acc[n][r16] += red[(size_t)(qw * 32 + qrow) * 128 + n * 32 + l31];
      }
  };
  if (jp == 1) DUMP(redK);
  if (jp == 2) DUMP(redV);
  __syncthreads();
  if (jp == 0) { ADD(redK); ADD(redV); }
  __syncthreads();
  if (jp == 3) DUMP(redK);
  __syncthreads();
  if (jp == 0) {
    ADD(redK);
    float ss[16];
#pragma unroll
    for (int r16 = 0; r16 < 16; ++r16) {
      float tt = 0.0f;
#pragma unroll
      for (int n = 0; n < 4; ++n) tt += acc[n][r16] * acc[n][r16];
      ss[r16] = tt;
    }
#pragma unroll
    for (int msk = 1; msk <= 16; msk <<= 1)
#pragma unroll
      for (int r16 = 0; r16 < 16; ++r16) ss[r16] += __shfl_xor(ss[r16], msk);
#pragma unroll
    for (int r16 = 0; r16 < 16; ++r16)
      ss[r16] = rsqrtf(ss[r16] * (1.0f / 128.0f) + 1e-6f);
    float* orow = out + ((size_t)((b * NH + h) * NS) + q0 + qw * 32) * ND;
#pragma unroll
    for (int n = 0; n < 4; ++n)
#pragma unroll
      for (int r16 = 0; r16 < 16; ++r16) {
        int qrow = (r16 & 3) + 8 * (r16 >> 2) + 4 * hh;
        orow[(size_t)qrow * ND + n * 32 + l31] = acc[n][r16] * ss[r16];
      }
  }
}

extern "C" void kernel_launch(void* const* d_in, const int* in_sizes, int n_in,
                              void* d_out, int out_size, void* d_ws, size_t ws_size,
                              hipStream_t stream) {
  const float* q  = (const float*)d_in[0];
  const float* k  = (const float*)d_in[1];
  const float* v  = (const float*)d_in[2];
  const float* om = (const float*)d_in[3];
  float* out = (float*)d_out;

  const int NELT = NB * NH * NS * ND;       // 4,194,304
  u16* kbuf = (u16*)d_ws;
  u16* vtb  = kbuf + NELT;

  prepass<<<4096 + 1024, 256, 0, stream>>>(k, v, kbuf, vtb);
  retention_main<<<256, 1024, 0, stream>>>(q, kbuf, vtb, om, out);
}